// Round 6
// baseline (1995.001 us; speedup 1.0000x reference)
//
#include <hip/hip_runtime.h>
#include <hip/hip_bf16.h>

// LinearformerBlock on MI355X (gfx950). I/O is FP32; internals bf16 MFMA with
// fp32 accumulation. B=4,N=4096,D=1024,H=4,DH=256,FF=4096.
//
// ws = 30,670,848 B — EXACTLY the proven baseline footprint.
//
// d_out (64MB fp32) doubles as scratch: first half = xln (bf16 LN1(x)),
// second half = x2 (bf16). Final dense writes fp32 rows forward-order;
// out chunk R clobbers x2 rows [2048R-16384, 2048R-14336). gemm1 reads the
// x2 copy rescued into G cols [4096:5120) (ffn_prep), so the only x2 readers
// in chunk R are prep itself. For R<15 prep's seed-clobber range stays below
// its own read range (overlap iff R>14); R=15 keeps split copy->seed order.
//
// r6: FFN algebra out = x2@wd + g@(wff2@wd) + (b2@wd+bd). 3682 -> 2904.
// r7: K-concat FFN epilogue + LN1 hoist (xln). 2904 -> 2468.
// r8: LDS XOR-swizzle + dbuf pipeline + fused KV. -> 2253.
// r9: out-GEMM z=4 + attention algebra (q~@CW). -> 1970.
// r10 (this round):
//  (a) T1 XCD-aware bijective block swizzle in gemm_bt (y-fastest flatten,
//      id=(orig&7)*nwg/8+orig>>3, nwg%8==0 guard): contiguous per-XCD chunks
//      share A/B panels (out-GEMM chunk working set 3.75MB ~ one 4MB L2).
//      Attacks FETCH 84MB vs ~45MB ideal on the 770us out-GEMM class.
//  (b) ffn_prep merges copy_cols+bias_bcast (R<15); gemm1 A <- G cols
//      [4096:5120) (lda 5120). Saves 15 launches.

typedef __hip_bfloat16 bf16;
typedef __attribute__((ext_vector_type(8))) short short8;
typedef __attribute__((ext_vector_type(4))) float floatx4;

__device__ __forceinline__ float b2f(bf16 x) { return __bfloat162float(x); }
__device__ __forceinline__ bf16 f2b(float x) { return __float2bfloat16(x); }
__device__ __forceinline__ float s2f(short s) {
  unsigned int u = ((unsigned int)(unsigned short)s) << 16;
  return __uint_as_float(u);
}
__device__ __forceinline__ short f2s(float f) {
  bf16 h = __float2bfloat16(f);
  return *reinterpret_cast<short*>(&h);
}
__device__ __forceinline__ float gelu_f(float x) {
  float u = 0.7978845608028654f * (x + 0.044715f * x * x * x);
  return 0.5f * x * (1.0f + tanhf(u));
}

// ---------------------------------------------------------------------------
// GEMM: C[m][n] = sum_k A'[m][k] * BT[n][k]   (A' = LN(A) if stats!=null)
// 128x128 tile, BK=32, 4 waves x (4x4) 16x16x32 bf16 MFMA.
// K must be a multiple of 64 and >= 64.
// LDS: double-buffered As/Bs with XOR-swizzled 16B slots (conflict-free).
// K-loop: 2-slice register prefetch, one barrier per slice.
// Block swizzle: XCD-aware bijection (y-fastest flatten) when nwg%8==0.
// AFP32: A operand fp32. CFP32: C fp32. TRANSC: C transposed (bf16, via LDS).
// ATOM: atomicAdd into fp32 C (split-K). RESF32: residual read as fp32.
// ---------------------------------------------------------------------------
template <int TRANSC, int AFP32, int CFP32, int ATOM, int RESF32 = 0>
__global__ __launch_bounds__(256) void gemm_bt(
    const void* __restrict__ Aop, const bf16* __restrict__ BT, void* Cv,
    int K, int lda, int ldb, int ldc, int zshift,
    long saA, long shA, long saB, long shB, long saC, long shC,
    const float* __restrict__ bias, const bf16* res, int act,
    const float2* stats, const float* __restrict__ gamma,
    const float* __restrict__ beta)
{
  // --- XCD-aware bijective block swizzle (y fastest, then x, then z) ---
  unsigned gx = gridDim.x, gy = gridDim.y;
  unsigned nxy = gx * gy, nwg = nxy * gridDim.z;
  unsigned orig = blockIdx.y + gy * (blockIdx.x + gx * blockIdx.z);
  unsigned sid = ((nwg & 7u) == 0u) ? ((orig & 7u) * (nwg >> 3) + (orig >> 3))
                                    : orig;
  unsigned bz = sid / nxy;
  unsigned rr = sid - bz * nxy;
  unsigned bxi = rr / gy, byi = rr - (rr / gy) * gy;

  int z = (int)bz;
  int zb = z >> zshift, zh = z & ((1 << zshift) - 1);
  long offA = (long)zb * saA + (long)zh * shA;
  long offC = (long)zb * saC + (long)zh * shC;
  const float* Af = (const float*)Aop + offA;
  const bf16*  Ab = (const bf16*)Aop + offA;
  BT += (long)zb * saB + (long)zh * shB;
  bf16*  C  = (bf16*)Cv + offC;
  float* Cf = (float*)Cv + offC;
  const bf16*  resb = res ? res + offC : nullptr;
  const float* resf = res ? (const float*)res + offC : nullptr;
  if (stats) stats += offA / lda;

  // smem: As = [2][128*32] at 0, Bs = [2][128*32] at 8192. TRANSC epilogue
  // aliases the whole region as TC[128*136] (safe: used after final barrier).
  __shared__ bf16 smem[TRANSC ? 128 * 136 : 16384];
  bf16* As = smem;
  bf16* Bs = smem + 8192;

  const int t = threadIdx.x;
  const int w = t >> 6, l = t & 63;
  const int m0 = (int)byi * 128, n0 = (int)bxi * 128;
  const int wm = (w >> 1) * 64, wn = (w & 1) * 64;
  const int lr = l & 15, lq = l >> 4;

  floatx4 acc[4][4] = {};

  const int sr = t >> 2;        // staging row within half-tile (0..63)
  const int sc = (t & 3) * 8;   // staging col (0,8,16,24)
  // swizzled 16B-slot store offset: slot s -> s ^ ((row>>1)&3).
  const int stO = sr * 32 + (((t & 3) ^ ((sr >> 1) & 3))) * 8;
  const int rowA0 = m0 + sr, rowA1 = m0 + 64 + sr;
  const long o0 = (long)rowA0 * lda + sc;
  const long o1 = (long)rowA1 * lda + sc;

  const bf16* Bp0 = BT + (long)(n0 + sr) * ldb + sc;
  const bf16* Bp1 = BT + (long)(n0 + 64 + sr) * ldb + sc;

  float2 st0, st1;
  if (stats) { st0 = stats[rowA0]; st1 = stats[rowA1]; }

  auto LOADSET = [&](int k0, short8& ra0, short8& ra1, short8& rb0, short8& rb1) {
    if constexpr (AFP32) {
      float4 a00 = *(const float4*)(Af + o0 + k0);
      float4 a01 = *(const float4*)(Af + o0 + k0 + 4);
      float4 a10 = *(const float4*)(Af + o1 + k0);
      float4 a11 = *(const float4*)(Af + o1 + k0 + 4);
      float v0[8] = {a00.x, a00.y, a00.z, a00.w, a01.x, a01.y, a01.z, a01.w};
      float v1[8] = {a10.x, a10.y, a10.z, a10.w, a11.x, a11.y, a11.z, a11.w};
      if (stats) {
        float4 g0 = *(const float4*)(gamma + k0 + sc);
        float4 g1 = *(const float4*)(gamma + k0 + sc + 4);
        float4 e0 = *(const float4*)(beta + k0 + sc);
        float4 e1 = *(const float4*)(beta + k0 + sc + 4);
        float gv[8] = {g0.x, g0.y, g0.z, g0.w, g1.x, g1.y, g1.z, g1.w};
        float ev[8] = {e0.x, e0.y, e0.z, e0.w, e1.x, e1.y, e1.z, e1.w};
#pragma unroll
        for (int i = 0; i < 8; i++) {
          v0[i] = (v0[i] - st0.x) * st0.y * gv[i] + ev[i];
          v1[i] = (v1[i] - st1.x) * st1.y * gv[i] + ev[i];
        }
      }
#pragma unroll
      for (int i = 0; i < 8; i++) { ra0[i] = f2s(v0[i]); ra1[i] = f2s(v1[i]); }
    } else {
      ra0 = *(const short8*)(Ab + o0 + k0);
      ra1 = *(const short8*)(Ab + o1 + k0);
      if (stats) {
        float4 g0 = *(const float4*)(gamma + k0 + sc);
        float4 g1 = *(const float4*)(gamma + k0 + sc + 4);
        float4 e0 = *(const float4*)(beta + k0 + sc);
        float4 e1 = *(const float4*)(beta + k0 + sc + 4);
        float gv[8] = {g0.x, g0.y, g0.z, g0.w, g1.x, g1.y, g1.z, g1.w};
        float ev[8] = {e0.x, e0.y, e0.z, e0.w, e1.x, e1.y, e1.z, e1.w};
#pragma unroll
        for (int i = 0; i < 8; i++) {
          ra0[i] = f2s((s2f(ra0[i]) - st0.x) * st0.y * gv[i] + ev[i]);
          ra1[i] = f2s((s2f(ra1[i]) - st1.x) * st1.y * gv[i] + ev[i]);
        }
      }
    }
    short8 b0 = *(const short8*)(Bp0 + k0);
    short8 b1 = *(const short8*)(Bp1 + k0);
    rb0 = b0; rb1 = b1;
  };

  auto STORESET = [&](int p, short8 ra0, short8 ra1, short8 rb0, short8 rb1) {
    *(short8*)&As[p * 4096 + stO]        = ra0;
    *(short8*)&As[p * 4096 + 2048 + stO] = ra1;
    *(short8*)&Bs[p * 4096 + stO]        = rb0;
    *(short8*)&Bs[p * 4096 + 2048 + stO] = rb1;
  };

  auto COMPUTE = [&](int p) {
    short8 af[4], bfr[4];
#pragma unroll
    for (int i = 0; i < 4; i++) {
      int Ra = wm + i * 16 + lr;
      int Rb = wn + i * 16 + lr;
      af[i]  = *(const short8*)&As[p * 4096 + Ra * 32 + (lq ^ ((Ra >> 1) & 3)) * 8];
      bfr[i] = *(const short8*)&Bs[p * 4096 + Rb * 32 + (lq ^ ((Rb >> 1) & 3)) * 8];
    }
#pragma unroll
    for (int i = 0; i < 4; i++)
#pragma unroll
      for (int j = 0; j < 4; j++)
        acc[i][j] = __builtin_amdgcn_mfma_f32_16x16x32_bf16(af[i], bfr[j], acc[i][j], 0, 0, 0);
  };

  // --- software-pipelined K loop: 2-slice reg prefetch, LDS double buffer ---
  short8 pa0, pa1, pb0, pb1, qa0, qa1, qb0, qb1;
  LOADSET(0,  pa0, pa1, pb0, pb1);
  LOADSET(32, qa0, qa1, qb0, qb1);
  STORESET(0, pa0, pa1, pb0, pb1);
  __syncthreads();
  const int nI = K >> 5;  // even, >= 2
  for (int it = 0; it < nI; it += 2) {
    if (it + 2 < nI) LOADSET((it + 2) * 32, pa0, pa1, pb0, pb1);
    COMPUTE(0);
    STORESET(1, qa0, qa1, qb0, qb1);
    __syncthreads();
    if (it + 3 < nI) LOADSET((it + 3) * 32, qa0, qa1, qb0, qb1);
    COMPUTE(1);
    if (it + 2 < nI) STORESET(0, pa0, pa1, pb0, pb1);
    __syncthreads();
  }

  if constexpr (TRANSC) {
    bf16* TC = smem;  // alias: all As/Bs reads are done (final barrier above)
    // C/D layout: col(n) = lane&15, row(m) = (lane>>4)*4 + reg.
#pragma unroll
    for (int i = 0; i < 4; i++) {
      int rloc = wm + i * 16 + lq * 4;
#pragma unroll
      for (int j = 0; j < 4; j++) {
        int cloc = wn + j * 16 + lr;
#pragma unroll
        for (int r = 0; r < 4; r++)
          TC[cloc * 136 + rloc + r] = f2b(acc[i][j][r]);
      }
    }
    __syncthreads();
    long base = (long)n0 * ldc + m0;
#pragma unroll
    for (int p = 0; p < 8; p++) {
      int er = (t >> 4) + p * 16;   // local e row (0..127)
      int mc = (t & 15) * 8;        // local m col
      *(short8*)(C + base + (long)er * ldc + mc) = *(const short8*)&TC[er * 136 + mc];
    }
    return;
  }

#pragma unroll
  for (int i = 0; i < 4; i++) {
    int row0 = m0 + wm + i * 16 + lq * 4;
#pragma unroll
    for (int j = 0; j < 4; j++) {
      int col = n0 + wn + j * 16 + lr;
      if constexpr (ATOM) {
#pragma unroll
        for (int r = 0; r < 4; r++) {
          long idx = (long)(row0 + r) * ldc + col;
          atomicAdd(&Cf[idx], acc[i][j][r]);
        }
      } else {
        float bv = bias ? bias[col] : 0.0f;
#pragma unroll
        for (int r = 0; r < 4; r++) {
          float v = acc[i][j][r] + bv;
          long idx = (long)(row0 + r) * ldc + col;
          if (res) {
            if constexpr (RESF32) v += resf[idx]; else v += b2f(resb[idx]);
          }
          if (act) v = gelu_f(v);
          if constexpr (CFP32) Cf[idx] = v; else C[idx] = f2b(v);
        }
      }
    }
  }
}

// ---------------------------------------------------------------------------
// Tiled transpose fp32 -> bf16: dst[c][r] = (bf16)src[r][c].
// Grid: (Csrc/32, Rsrc/32). Block (32,8).
// ---------------------------------------------------------------------------
__global__ void transpose_f2b(const float* __restrict__ src, bf16* __restrict__ dst,
                              int lsrc, int ldst)
{
  __shared__ bf16 tile[32][33];
  int tx = threadIdx.x, ty = threadIdx.y;
  int c0 = blockIdx.x * 32, r0 = blockIdx.y * 32;
#pragma unroll
  for (int j = 0; j < 4; j++)
    tile[ty + j * 8][tx] = f2b(src[(long)(r0 + ty + j * 8) * lsrc + c0 + tx]);
  __syncthreads();
#pragma unroll
  for (int j = 0; j < 4; j++)
    dst[(long)(c0 + ty + j * 8) * ldst + r0 + tx] = tile[tx][ty + j * 8];
}

// FFN chunk prep (R<15): row r: G[r][4096:5120) = x2c[r][:]; out[r][:] = OB.
__global__ __launch_bounds__(256) void ffn_prep(
    const bf16* __restrict__ x2c, const float* __restrict__ OB,
    bf16* __restrict__ G, float* __restrict__ out)
{
  int r = blockIdx.x, t = threadIdx.x;
  if (t < 128)
    *(short8*)(G + (long)r * 5120 + 4096 + t * 8) =
        *(const short8*)(x2c + (long)r * 1024 + t * 8);
  *(float4*)(out + (long)r * 1024 + t * 4) = *(const float4*)(OB + t * 4);
}

// copy x2 chunk row r cols [0,1024) -> G row r cols [4096,5120). (R=15 path)
__global__ __launch_bounds__(128) void copy_cols(const bf16* __restrict__ s,
                                                 bf16* __restrict__ d)
{
  int r = blockIdx.x, c = threadIdx.x * 8;
  *(short8*)(d + (long)r * 5120 + 4096 + c) = *(const short8*)(s + (long)r * 1024 + c);
}

// LN stats over D=1024: stats[row] = {mean, rsqrt(var+eps)}. fp32 input.
__global__ __launch_bounds__(256) void ln_stats_f32(
    const float* __restrict__ x, float2* __restrict__ stats)
{
  int row = blockIdx.x, t = threadIdx.x;
  const float* xr = x + (long)row * 1024;
  float4 a = *(const float4*)(xr + t * 4);
  float s = a.x + a.y + a.z + a.w;
  float q = a.x * a.x + a.y * a.y + a.z * a.z + a.w * a.w;
  for (int o = 32; o > 0; o >>= 1) { s += __shfl_down(s, o); q += __shfl_down(q, o); }
  __shared__ float sm[8];
  if ((t & 63) == 0) { sm[t >> 6] = s; sm[4 + (t >> 6)] = q; }
  __syncthreads();
  if (t == 0) {
    s = sm[0] + sm[1] + sm[2] + sm[3];
    q = sm[4] + sm[5] + sm[6] + sm[7];
    float mean = s * (1.0f / 1024.0f);
    float var  = q * (1.0f / 1024.0f) - mean * mean;
    stats[row] = make_float2(mean, rsqrtf(var + 1e-5f));
  }
}

// xln[i] = bf16((x[i]-mu)*rstd*g+b), 8 elems/thread (all within one row).
__global__ __launch_bounds__(256) void ln_apply(
    const float* __restrict__ x, const float2* __restrict__ stats,
    const float* __restrict__ g, const float* __restrict__ b,
    bf16* __restrict__ out)
{
  long i = ((long)blockIdx.x * 256 + threadIdx.x) * 8;
  int row = (int)(i >> 10), col = (int)(i & 1023);
  float2 st = stats[row];
  float4 a0 = *(const float4*)(x + i);
  float4 a1 = *(const float4*)(x + i + 4);
  float4 g0 = *(const float4*)(g + col);
  float4 g1 = *(const float4*)(g + col + 4);
  float4 b0 = *(const float4*)(b + col);
  float4 b1 = *(const float4*)(b + col + 4);
  float av[8] = {a0.x, a0.y, a0.z, a0.w, a1.x, a1.y, a1.z, a1.w};
  float gv[8] = {g0.x, g0.y, g0.z, g0.w, g1.x, g1.y, g1.z, g1.w};
  float bv[8] = {b0.x, b0.y, b0.z, b0.w, b1.x, b1.y, b1.z, b1.w};
  short8 o;
#pragma unroll
  for (int j = 0; j < 8; j++)
    o[j] = f2s((av[j] - st.x) * st.y * gv[j] + bv[j]);
  *(short8*)(out + i) = o;
}

// LN stats, bf16 input.
__global__ __launch_bounds__(256) void ln_stats_b16(
    const bf16* __restrict__ x, float2* __restrict__ stats)
{
  int row = blockIdx.x, t = threadIdx.x;
  const bf16* xr = x + (long)row * 1024;
  float v[4];
#pragma unroll
  for (int i = 0; i < 4; i++) v[i] = b2f(xr[t * 4 + i]);
  float s = v[0] + v[1] + v[2] + v[3];
  float q = v[0] * v[0] + v[1] * v[1] + v[2] * v[2] + v[3] * v[3];
  for (int o = 32; o > 0; o >>= 1) { s += __shfl_down(s, o); q += __shfl_down(q, o); }
  __shared__ float sm[8];
  if ((t & 63) == 0) { sm[t >> 6] = s; sm[4 + (t >> 6)] = q; }
  __syncthreads();
  if (t == 0) {
    s = sm[0] + sm[1] + sm[2] + sm[3];
    q = sm[4] + sm[5] + sm[6] + sm[7];
    float mean = s * (1.0f / 1024.0f);
    float var  = q * (1.0f / 1024.0f) - mean * mean;
    stats[row] = make_float2(mean, rsqrtf(var + 1e-5f));
  }
}

// softmax over 256 contiguous elems per row (q~, per-head seg). In place, bf16.
__global__ __launch_bounds__(256) void qsoftmax256(bf16* __restrict__ q)
{
  long idx = (long)blockIdx.x * 256 + threadIdx.x;
  int t = threadIdx.x;
  float v = expf(0.25f * b2f(q[idx]));
  float s = v;
  for (int o = 32; o > 0; o >>= 1) s += __shfl_down(s, o);
  __shared__ float sm[4];
  if ((t & 63) == 0) sm[t >> 6] = s;
  __syncthreads();
  float tot = sm[0] + sm[1] + sm[2] + sm[3];
  q[idx] = f2b(v / tot);
}

// k softmax on fused KV buffer [4b][512e][4096n]: rows e<256 of each batch
// are k~; row-softmax exp(0.25x)/rowsum in place.
__global__ __launch_bounds__(256) void ksoftmaxKV(bf16* __restrict__ kv)
{
  int b = blockIdx.x >> 8, e = blockIdx.x & 255;
  long base = ((long)b * 512 + e) * 4096;
  int t = threadIdx.x;
  float loc[16];
  float s = 0.0f;
#pragma unroll
  for (int i = 0; i < 16; i++) {
    loc[i] = expf(0.25f * b2f(kv[base + t + i * 256]));
    s += loc[i];
  }
  for (int o = 32; o > 0; o >>= 1) s += __shfl_down(s, o);
  __shared__ float sm[4];
  if ((t & 63) == 0) sm[t >> 6] = s;
  __syncthreads();
  float inv = 1.0f / (sm[0] + sm[1] + sm[2] + sm[3]);
#pragma unroll
  for (int i = 0; i < 16; i++)
    kv[base + t + i * 256] = f2b(loc[i] * inv);
}

// ctx reduce: dst[b*262144 + j] = sum_{kc<16} G[kc*262144 + b*65536 + j].
// dst base is CTXT + h*65536 (head-interleaved [b][h][256d][256e]).
__global__ __launch_bounds__(256) void reduce_ctx(
    const bf16* __restrict__ G, bf16* __restrict__ dst)
{
  long i = (long)blockIdx.x * 256 + threadIdx.x;  // [0, 262144)
  float s = 0.0f;
#pragma unroll
  for (int kc = 0; kc < 16; kc++) s += b2f(G[kc * 262144 + i]);
  dst[(i >> 16) * 262144 + (i & 65535)] = f2b(s);
}

// OB[n] = sum_k b2[k] * wdt[n][k] + bd[n]   (n = blockIdx.x; wdt row stride ld)
__global__ __launch_bounds__(256) void out_bias(
    const float* __restrict__ b2, const bf16* __restrict__ wdt, int ld,
    const float* __restrict__ bd, float* __restrict__ OB)
{
  int n = blockIdx.x, t = threadIdx.x;
  const bf16* wr = wdt + (long)n * ld;
  float s = 0.0f;
#pragma unroll
  for (int i = 0; i < 4; i++) {
    int k = t * 4 + i;
    s += b2[k] * b2f(wr[k]);
  }
  for (int o = 32; o > 0; o >>= 1) s += __shfl_down(s, o);
  __shared__ float sm[4];
  if ((t & 63) == 0) sm[t >> 6] = s;
  __syncthreads();
  if (t == 0) OB[n] = sm[0] + sm[1] + sm[2] + sm[3] + bd[n];
}

// out[r][c] = b[c] over 1024x1024 fp32 (seed for atomic split-K GEMMs)
__global__ __launch_bounds__(256) void bias_bcast(
    const float* __restrict__ b, float* __restrict__ out)
{
  long i = ((long)blockIdx.x * 256 + threadIdx.x) * 4;
  *(float4*)(out + i) = *(const float4*)(b + (int)(i & 1023));
}

extern "C" void kernel_launch(void* const* d_in, const int* in_sizes, int n_in,
                              void* d_out, int out_size, void* d_ws, size_t ws_size,
                              hipStream_t stream) {
  const float* x    = (const float*)d_in[0];
  const float* ln1g = (const float*)d_in[1];
  const float* ln1b = (const float*)d_in[2];
  const float* wq   = (const float*)d_in[3];
  const float* wk   = (const float*)d_in[4];
  const float* wv   = (const float*)d_in[5];
  const float* wo   = (const float*)d_in[6];
  const float* bo   = (const float*)d_in[7];
  const float* ln2g = (const float*)d_in[8];
  const float* ln2b = (const float*)d_in[9];
  const float* wff1 = (const float*)d_in[10];
  const float* bff1 = (const float*)d_in[11];
  const float* wff2 = (const float*)d_in[12];
  const float* bff2 = (const float*)d_in[13];
  const float* wd   = (const float*)d_in[14];
  const float* bd   = (const float*)d_in[15];

  // d_out (64MB fp32) as scratch: first half xln (bf16 LN1(x)), second x2.
  bf16* xln = (bf16*)d_out;                           // 16384x1024 bf16
  bf16* x2  = (bf16*)d_out + (size_t)16384 * 1024;    // 16384x1024 bf16
  float* outf = (float*)d_out;

  char* wsp = (char*)d_ws;
  size_t off = 0;
  auto alloc = [&](size_t bytes) -> void* {
    void* p = wsp + off; off += (bytes + 255) & ~(size_t)255; return p;
  };
  bf16*   S1  = (bf16*)alloc((size_t)8 * 1024 * 1024);    // KV lo | q~ lo | wff1T
  bf16*   S2  = (bf16*)alloc((size_t)10 * 1024 * 1024);   // KV hi | q~ hi | WB
  bf16*   G   = (bf16*)alloc((size_t)10 * 1024 * 1024);   // ctx partials | CWT | [g|x2_R]
  bf16*   CTX = (bf16*)alloc((size_t)4 * 256 * 256 * 2);  // OB overlay (FFN)
  bf16*   W1  = (bf16*)alloc((size_t)1024 * 256 * 2);     // (spare)
  float2* st1 = (float2*)alloc((size_t)16384 * 8);
  float2* st2 = (float2*)alloc((size_t)16384 * 8);
  bf16*   KV   = S1;                           // [4b][512e][4096n] = 16MB (S1+S2)
  bf16*   W1kv = G + (size_t)9 * 512 * 1024;   // G bytes [9MB,10MB): [512][1024]
  bf16*   CTXT = S2 + (size_t)4 * 1024 * 1024; // S2 bytes [8MB,10MB): [4b][4h][256][256]
  bf16*   woT  = G + (size_t)4 * 1024 * 1024;  // G bytes [8MB,10MB): [1024][1024]
  bf16*   CWT  = G;                            // G bytes [0,8MB): [4b][1024c][1024hd]
  bf16*   wqT  = CTXT;                         // reuse after CWT built
  bf16*   QB   = S1;                           // q~ pair buffer [8192][1024] (16MB)
  bf16*   WB   = S2;                           // FFN: [1024][5120] = [WCD^T|wd^T]
  float*  OB   = (float*)CTX;                  // 4KB, FFN phase
  // total ws = 30,670,848 B — identical to the proven baseline footprint.

  const long SA  = (long)4096 * 1024;  // per-batch xln row stride (elements)
  const long PKV = (long)512 * 4096;   // per-batch KV [e][n] stride
  dim3 tb(32, 8);
  const bf16* nb = nullptr;

  // ---- LN1 stats + xln = bf16(LN1(x)) ----
  ln_stats_f32<<<16384, 256, 0, stream>>>(x, st1);
  ln_apply<<<8192, 256, 0, stream>>>(x, st1, ln1g, ln1b, xln);

  // ---- attention phase 1: per head, KV + context[d][e] ----
  for (int h = 0; h < 4; h++) {
    // KV = (xln @ [wk_h|wv_h])^T -> [4b][512e][4096n]; k rows then v rows.
    transpose_f2b<<<dim3(8, 32), tb, 0, stream>>>(wk + h * 256, W1kv, 1024, 1024);
    transpose_f2b<<<dim3(8, 32), tb, 0, stream>>>(wv + h * 256, W1kv + 256 * 1024, 1024, 1024);
    gemm_bt<1, 0, 0, 0><<<dim3(4, 32, 4), 256, 0, stream>>>(xln, W1kv, KV,
        1024, 1024, 1024, 4096, 2, 0, SA, 0, 0, 0, PKV,
        nullptr, nb, 0, nullptr, nullptr, nullptr);
    ksoftmaxKV<<<1024, 256, 0, stream>>>(KV);

    // ctx partials: G[kc][b][d][e] = sum_{n in kc} k~[d][n] * v[e][n]
    // (16 seq-chunks of 256 -> 256 blocks)
    gemm_bt<0, 0, 0, 0><<<dim3(2, 2, 64), 256, 0, stream>>>(KV, KV + (long)256 * 4096, G,
        256, 4096, 4096, 256, 4, PKV, 256, PKV, 256, 65536, 262144,
        nullptr, nb, 0, nullptr, nullptr, nullptr);
    reduce_ctx<<<1024, 256, 0, stream>>>(G, CTXT + h * 65536);
  }

  // ---- attention phase 1.5: CWT[b][c][(h,d)] = sum_e wo_h[e][c]*ctx_h[d][e] ----
  transpose_f2b<<<dim3(32, 32), tb, 0, stream>>>(wo, woT, 1024, 1024);
  gemm_bt<0, 0, 0, 0><<<dim3(2, 8, 16), 256, 0, stream>>>(woT, CTXT, CWT,
      256, 1024, 256, 1024, 2, 0, 256, 262144, 65536, 1048576, 256,
      nullptr, nb, 0, nullptr, nullptr, nullptr);
  transpose_f2b<<<dim3(32, 32), tb, 0, stream>>>(wq, wqT, 1024, 1024);  // CTXT dead

  // ---- attention phase 2: per batch-pair, q~ (all heads) then x2 ----
  for (int p = 0; p < 2; p++) {
    // q = xln_pair @ wq (all heads) -> QB [8192][1024]
    gemm_bt<0, 0, 0, 0><<<dim3(8, 64, 1), 256, 0, stream>>>(
        xln + (size_t)p * 8192 * 1024, wqT, QB,
        1024, 1024, 1024, 1024, 0, 0, 0, 0, 0, 0, 0,
        nullptr, nb, 0, nullptr, nullptr, nullptr);
    qsoftmax256<<<32768, 256, 0, stream>>>(QB);
    // x2_pair = x_pair + bo + q~ @ CWT[b]  (z = batch-in-pair)
    gemm_bt<0, 0, 0, 0, 1><<<dim3(8, 32, 2), 256, 0, stream>>>(
        QB, CWT + (size_t)p * 2 * 1048576, x2 + (size_t)p * 8192 * 1024,
        1024, 1024, 1024, 1024, 1, 0, SA, 0, 1048576, 0, SA,
        bo, (const bf16*)(x + (size_t)p * 8192 * 1024), 0,
        nullptr, nullptr, nullptr);
  }

  // ---- FFN + trailing dense: out = [g|x2_R] @ [WCD^T|wd^T]^T + OB ----
  ln_stats_b16<<<16384, 256, 0, stream>>>(x2, st2);
  transpose_f2b<<<dim3(128, 32), tb, 0, stream>>>(wff1, S1, 4096, 1024);  // S1 = wff1T
  // WB cols [4096:5120) = wd^T  (row stride 5120)
  transpose_f2b<<<dim3(32, 32), tb, 0, stream>>>(wd, WB + 4096, 1024, 5120);
  // WB cols [0:4096) = WCD^T = (wff2@wd)^T; B operand = wd^T slice of WB.
  gemm_bt<1, 1, 0, 0><<<dim3(8, 32, 1), 256, 0, stream>>>(wff2, WB + 4096, WB,
      1024, 1024, 5120, 5120, 0, 0, 0, 0, 0, 0, 0,
      nullptr, nb, 0, nullptr, nullptr, nullptr);
  // OB[n] = b_ff2 @ wd + b_d
  out_bias<<<1024, 256, 0, stream>>>(bff2, WB + 4096, 5120, bd, OB);

  for (int R = 0; R < 16; R++) {
    const bf16* xr = x2 + (size_t)R * 1024 * 1024;  // x2 rows (bf16)
    float* outR = outf + (size_t)R * 1024 * 1024;
    if (R < 15) {
      // prep: G cols [4096:5120) = x2_R; out_R = OB. Seed-clobber of x2 rows
      // [2048R-16384,2048R-14336) is below prep's own read rows for R<15.
      ffn_prep<<<1024, 256, 0, stream>>>(xr, OB, G, outR);
    } else {
      // R=15: seed clobbers x2 rows prep reads -> copy first, then seed.
      copy_cols<<<1024, 128, 0, stream>>>(xr, G);
      bias_bcast<<<1024, 256, 0, stream>>>(OB, outR);
    }
    // G cols [0:4096) = gelu(LN2(x2_R) @ wff1T + b1); A = rescued x2 copy.
    gemm_bt<0, 0, 0, 0><<<dim3(32, 8, 1), 256, 0, stream>>>(G + 4096, S1, G,
        1024, 5120, 1024, 5120, 2, 0, 0, 0, 0, 0, 0,
        bff1, nb, 1, st2 + R * 1024, ln2g, ln2b);
    // out_R += [g|x2_R] @ WB^T  (split-K: z=4 slices of K=1280 -> 256 blocks)
    gemm_bt<0, 0, 1, 1><<<dim3(8, 8, 4), 256, 0, stream>>>(G, WB, outR,
        1280, 5120, 5120, 1024, 2, 0, 1280, 0, 1280, 0, 0,
        nullptr, nb, 0, nullptr, nullptr, nullptr);
  }
}

// Round 7
// 1953.196 us; speedup vs baseline: 1.0214x; 1.0214x over previous
//
#include <hip/hip_runtime.h>
#include <hip/hip_bf16.h>

// LinearformerBlock on MI355X (gfx950). I/O is FP32; internals bf16 MFMA with
// fp32 accumulation. B=4,N=4096,D=1024,H=4,DH=256,FF=4096.
//
// ws = 30,670,848 B — EXACTLY the proven baseline footprint.
//
// d_out (64MB fp32) doubles as scratch: first half = xln (bf16 LN1(x)),
// second half = x2 (bf16). Final dense writes fp32 rows forward-order;
// out chunk R clobbers x2 rows [2048R-16384, 2048R-14336). gemm1 reads the
// x2 copy rescued into G cols [4096:5120) (ffn_prep); R=15 keeps split
// copy->seed order (its seed clobbers its own x2 source rows).
//
// r6: FFN algebra out = x2@wd + g@(wff2@wd) + (b2@wd+bd). 3682 -> 2904.
// r7: K-concat FFN epilogue + LN1 hoist (xln). 2904 -> 2468.
// r8: LDS XOR-swizzle + dbuf pipeline + fused KV. -> 2253.
// r9: out-GEMM z=4 + attention algebra (q~@CW). -> 1970.
// r10: XCD swizzle (y-fastest flatten) — REGRESSED to 1995: HW dispatches
//      x-fastest, so orig&7 != XCD; gemm1's natural 3MB/XCD working set was
//      destroyed (each XCD read all 8MB of wff1T -> FETCH 34MB, 51us).
// r11 (this round): HW-ALIGNED swizzle: hw = x + gx*(y + gy*z) (actual
//      dispatch order, XCD = hw&7); wid = (hw&7)*nwg/8 + hw>>3; decode wid
//      y-fastest. Per-XCD working sets: gemm1 = 3MB (B-slice constant across
//      all 16 chunks -> L2-resident), out-GEMM = 3.75MB. Single-variable fix.

typedef __hip_bfloat16 bf16;
typedef __attribute__((ext_vector_type(8))) short short8;
typedef __attribute__((ext_vector_type(4))) float floatx4;

__device__ __forceinline__ float b2f(bf16 x) { return __bfloat162float(x); }
__device__ __forceinline__ bf16 f2b(float x) { return __float2bfloat16(x); }
__device__ __forceinline__ float s2f(short s) {
  unsigned int u = ((unsigned int)(unsigned short)s) << 16;
  return __uint_as_float(u);
}
__device__ __forceinline__ short f2s(float f) {
  bf16 h = __float2bfloat16(f);
  return *reinterpret_cast<short*>(&h);
}
__device__ __forceinline__ float gelu_f(float x) {
  float u = 0.7978845608028654f * (x + 0.044715f * x * x * x);
  return 0.5f * x * (1.0f + tanhf(u));
}

// ---------------------------------------------------------------------------
// GEMM: C[m][n] = sum_k A'[m][k] * BT[n][k]   (A' = LN(A) if stats!=null)
// 128x128 tile, BK=32, 4 waves x (4x4) 16x16x32 bf16 MFMA.
// K must be a multiple of 64 and >= 64.
// LDS: double-buffered As/Bs with XOR-swizzled 16B slots (conflict-free).
// K-loop: 2-slice register prefetch, one barrier per slice.
// Block swizzle: XCD chunking aligned with HW dispatch order (x fastest);
// work id decoded y-fastest. Active only when nwg%8==0.
// AFP32: A operand fp32. CFP32: C fp32. TRANSC: C transposed (bf16, via LDS).
// ATOM: atomicAdd into fp32 C (split-K). RESF32: residual read as fp32.
// ---------------------------------------------------------------------------
template <int TRANSC, int AFP32, int CFP32, int ATOM, int RESF32 = 0>
__global__ __launch_bounds__(256) void gemm_bt(
    const void* __restrict__ Aop, const bf16* __restrict__ BT, void* Cv,
    int K, int lda, int ldb, int ldc, int zshift,
    long saA, long shA, long saB, long shB, long saC, long shC,
    const float* __restrict__ bias, const bf16* res, int act,
    const float2* stats, const float* __restrict__ gamma,
    const float* __restrict__ beta)
{
  // --- XCD-aware swizzle, aligned with HW dispatch order (x fastest) ---
  unsigned gx = gridDim.x, gy = gridDim.y;
  unsigned nxy = gx * gy, nwg = nxy * gridDim.z;
  unsigned hw = blockIdx.x + gx * (blockIdx.y + gy * blockIdx.z);
  unsigned wid = ((nwg & 7u) == 0u) ? ((hw & 7u) * (nwg >> 3) + (hw >> 3)) : hw;
  // decode wid y-fastest (m fastest), then x (n), then z
  unsigned bz = wid / nxy;
  unsigned rr = wid - bz * nxy;
  unsigned bxi = rr / gy, byi = rr - (rr / gy) * gy;

  int z = (int)bz;
  int zb = z >> zshift, zh = z & ((1 << zshift) - 1);
  long offA = (long)zb * saA + (long)zh * shA;
  long offC = (long)zb * saC + (long)zh * shC;
  const float* Af = (const float*)Aop + offA;
  const bf16*  Ab = (const bf16*)Aop + offA;
  BT += (long)zb * saB + (long)zh * shB;
  bf16*  C  = (bf16*)Cv + offC;
  float* Cf = (float*)Cv + offC;
  const bf16*  resb = res ? res + offC : nullptr;
  const float* resf = res ? (const float*)res + offC : nullptr;
  if (stats) stats += offA / lda;

  // smem: As = [2][128*32] at 0, Bs = [2][128*32] at 8192. TRANSC epilogue
  // aliases the whole region as TC[128*136] (safe: used after final barrier).
  __shared__ bf16 smem[TRANSC ? 128 * 136 : 16384];
  bf16* As = smem;
  bf16* Bs = smem + 8192;

  const int t = threadIdx.x;
  const int w = t >> 6, l = t & 63;
  const int m0 = (int)byi * 128, n0 = (int)bxi * 128;
  const int wm = (w >> 1) * 64, wn = (w & 1) * 64;
  const int lr = l & 15, lq = l >> 4;

  floatx4 acc[4][4] = {};

  const int sr = t >> 2;        // staging row within half-tile (0..63)
  const int sc = (t & 3) * 8;   // staging col (0,8,16,24)
  // swizzled 16B-slot store offset: slot s -> s ^ ((row>>1)&3).
  const int stO = sr * 32 + (((t & 3) ^ ((sr >> 1) & 3))) * 8;
  const int rowA0 = m0 + sr, rowA1 = m0 + 64 + sr;
  const long o0 = (long)rowA0 * lda + sc;
  const long o1 = (long)rowA1 * lda + sc;

  const bf16* Bp0 = BT + (long)(n0 + sr) * ldb + sc;
  const bf16* Bp1 = BT + (long)(n0 + 64 + sr) * ldb + sc;

  float2 st0, st1;
  if (stats) { st0 = stats[rowA0]; st1 = stats[rowA1]; }

  auto LOADSET = [&](int k0, short8& ra0, short8& ra1, short8& rb0, short8& rb1) {
    if constexpr (AFP32) {
      float4 a00 = *(const float4*)(Af + o0 + k0);
      float4 a01 = *(const float4*)(Af + o0 + k0 + 4);
      float4 a10 = *(const float4*)(Af + o1 + k0);
      float4 a11 = *(const float4*)(Af + o1 + k0 + 4);
      float v0[8] = {a00.x, a00.y, a00.z, a00.w, a01.x, a01.y, a01.z, a01.w};
      float v1[8] = {a10.x, a10.y, a10.z, a10.w, a11.x, a11.y, a11.z, a11.w};
      if (stats) {
        float4 g0 = *(const float4*)(gamma + k0 + sc);
        float4 g1 = *(const float4*)(gamma + k0 + sc + 4);
        float4 e0 = *(const float4*)(beta + k0 + sc);
        float4 e1 = *(const float4*)(beta + k0 + sc + 4);
        float gv[8] = {g0.x, g0.y, g0.z, g0.w, g1.x, g1.y, g1.z, g1.w};
        float ev[8] = {e0.x, e0.y, e0.z, e0.w, e1.x, e1.y, e1.z, e1.w};
#pragma unroll
        for (int i = 0; i < 8; i++) {
          v0[i] = (v0[i] - st0.x) * st0.y * gv[i] + ev[i];
          v1[i] = (v1[i] - st1.x) * st1.y * gv[i] + ev[i];
        }
      }
#pragma unroll
      for (int i = 0; i < 8; i++) { ra0[i] = f2s(v0[i]); ra1[i] = f2s(v1[i]); }
    } else {
      ra0 = *(const short8*)(Ab + o0 + k0);
      ra1 = *(const short8*)(Ab + o1 + k0);
      if (stats) {
        float4 g0 = *(const float4*)(gamma + k0 + sc);
        float4 g1 = *(const float4*)(gamma + k0 + sc + 4);
        float4 e0 = *(const float4*)(beta + k0 + sc);
        float4 e1 = *(const float4*)(beta + k0 + sc + 4);
        float gv[8] = {g0.x, g0.y, g0.z, g0.w, g1.x, g1.y, g1.z, g1.w};
        float ev[8] = {e0.x, e0.y, e0.z, e0.w, e1.x, e1.y, e1.z, e1.w};
#pragma unroll
        for (int i = 0; i < 8; i++) {
          ra0[i] = f2s((s2f(ra0[i]) - st0.x) * st0.y * gv[i] + ev[i]);
          ra1[i] = f2s((s2f(ra1[i]) - st1.x) * st1.y * gv[i] + ev[i]);
        }
      }
    }
    short8 b0 = *(const short8*)(Bp0 + k0);
    short8 b1 = *(const short8*)(Bp1 + k0);
    rb0 = b0; rb1 = b1;
  };

  auto STORESET = [&](int p, short8 ra0, short8 ra1, short8 rb0, short8 rb1) {
    *(short8*)&As[p * 4096 + stO]        = ra0;
    *(short8*)&As[p * 4096 + 2048 + stO] = ra1;
    *(short8*)&Bs[p * 4096 + stO]        = rb0;
    *(short8*)&Bs[p * 4096 + 2048 + stO] = rb1;
  };

  auto COMPUTE = [&](int p) {
    short8 af[4], bfr[4];
#pragma unroll
    for (int i = 0; i < 4; i++) {
      int Ra = wm + i * 16 + lr;
      int Rb = wn + i * 16 + lr;
      af[i]  = *(const short8*)&As[p * 4096 + Ra * 32 + (lq ^ ((Ra >> 1) & 3)) * 8];
      bfr[i] = *(const short8*)&Bs[p * 4096 + Rb * 32 + (lq ^ ((Rb >> 1) & 3)) * 8];
    }
#pragma unroll
    for (int i = 0; i < 4; i++)
#pragma unroll
      for (int j = 0; j < 4; j++)
        acc[i][j] = __builtin_amdgcn_mfma_f32_16x16x32_bf16(af[i], bfr[j], acc[i][j], 0, 0, 0);
  };

  // --- software-pipelined K loop: 2-slice reg prefetch, LDS double buffer ---
  short8 pa0, pa1, pb0, pb1, qa0, qa1, qb0, qb1;
  LOADSET(0,  pa0, pa1, pb0, pb1);
  LOADSET(32, qa0, qa1, qb0, qb1);
  STORESET(0, pa0, pa1, pb0, pb1);
  __syncthreads();
  const int nI = K >> 5;  // even, >= 2
  for (int it = 0; it < nI; it += 2) {
    if (it + 2 < nI) LOADSET((it + 2) * 32, pa0, pa1, pb0, pb1);
    COMPUTE(0);
    STORESET(1, qa0, qa1, qb0, qb1);
    __syncthreads();
    if (it + 3 < nI) LOADSET((it + 3) * 32, qa0, qa1, qb0, qb1);
    COMPUTE(1);
    if (it + 2 < nI) STORESET(0, pa0, pa1, pb0, pb1);
    __syncthreads();
  }

  if constexpr (TRANSC) {
    bf16* TC = smem;  // alias: all As/Bs reads are done (final barrier above)
    // C/D layout: col(n) = lane&15, row(m) = (lane>>4)*4 + reg.
#pragma unroll
    for (int i = 0; i < 4; i++) {
      int rloc = wm + i * 16 + lq * 4;
#pragma unroll
      for (int j = 0; j < 4; j++) {
        int cloc = wn + j * 16 + lr;
#pragma unroll
        for (int r = 0; r < 4; r++)
          TC[cloc * 136 + rloc + r] = f2b(acc[i][j][r]);
      }
    }
    __syncthreads();
    long base = (long)n0 * ldc + m0;
#pragma unroll
    for (int p = 0; p < 8; p++) {
      int er = (t >> 4) + p * 16;   // local e row (0..127)
      int mc = (t & 15) * 8;        // local m col
      *(short8*)(C + base + (long)er * ldc + mc) = *(const short8*)&TC[er * 136 + mc];
    }
    return;
  }

#pragma unroll
  for (int i = 0; i < 4; i++) {
    int row0 = m0 + wm + i * 16 + lq * 4;
#pragma unroll
    for (int j = 0; j < 4; j++) {
      int col = n0 + wn + j * 16 + lr;
      if constexpr (ATOM) {
#pragma unroll
        for (int r = 0; r < 4; r++) {
          long idx = (long)(row0 + r) * ldc + col;
          atomicAdd(&Cf[idx], acc[i][j][r]);
        }
      } else {
        float bv = bias ? bias[col] : 0.0f;
#pragma unroll
        for (int r = 0; r < 4; r++) {
          float v = acc[i][j][r] + bv;
          long idx = (long)(row0 + r) * ldc + col;
          if (res) {
            if constexpr (RESF32) v += resf[idx]; else v += b2f(resb[idx]);
          }
          if (act) v = gelu_f(v);
          if constexpr (CFP32) Cf[idx] = v; else C[idx] = f2b(v);
        }
      }
    }
  }
}

// ---------------------------------------------------------------------------
// Tiled transpose fp32 -> bf16: dst[c][r] = (bf16)src[r][c].
// Grid: (Csrc/32, Rsrc/32). Block (32,8).
// ---------------------------------------------------------------------------
__global__ void transpose_f2b(const float* __restrict__ src, bf16* __restrict__ dst,
                              int lsrc, int ldst)
{
  __shared__ bf16 tile[32][33];
  int tx = threadIdx.x, ty = threadIdx.y;
  int c0 = blockIdx.x * 32, r0 = blockIdx.y * 32;
#pragma unroll
  for (int j = 0; j < 4; j++)
    tile[ty + j * 8][tx] = f2b(src[(long)(r0 + ty + j * 8) * lsrc + c0 + tx]);
  __syncthreads();
#pragma unroll
  for (int j = 0; j < 4; j++)
    dst[(long)(c0 + ty + j * 8) * ldst + r0 + tx] = tile[tx][ty + j * 8];
}

// FFN chunk prep (R<15): row r: G[r][4096:5120) = x2c[r][:]; out[r][:] = OB.
__global__ __launch_bounds__(256) void ffn_prep(
    const bf16* __restrict__ x2c, const float* __restrict__ OB,
    bf16* __restrict__ G, float* __restrict__ out)
{
  int r = blockIdx.x, t = threadIdx.x;
  if (t < 128)
    *(short8*)(G + (long)r * 5120 + 4096 + t * 8) =
        *(const short8*)(x2c + (long)r * 1024 + t * 8);
  *(float4*)(out + (long)r * 1024 + t * 4) = *(const float4*)(OB + t * 4);
}

// copy x2 chunk row r cols [0,1024) -> G row r cols [4096,5120). (R=15 path)
__global__ __launch_bounds__(128) void copy_cols(const bf16* __restrict__ s,
                                                 bf16* __restrict__ d)
{
  int r = blockIdx.x, c = threadIdx.x * 8;
  *(short8*)(d + (long)r * 5120 + 4096 + c) = *(const short8*)(s + (long)r * 1024 + c);
}

// LN stats over D=1024: stats[row] = {mean, rsqrt(var+eps)}. fp32 input.
__global__ __launch_bounds__(256) void ln_stats_f32(
    const float* __restrict__ x, float2* __restrict__ stats)
{
  int row = blockIdx.x, t = threadIdx.x;
  const float* xr = x + (long)row * 1024;
  float4 a = *(const float4*)(xr + t * 4);
  float s = a.x + a.y + a.z + a.w;
  float q = a.x * a.x + a.y * a.y + a.z * a.z + a.w * a.w;
  for (int o = 32; o > 0; o >>= 1) { s += __shfl_down(s, o); q += __shfl_down(q, o); }
  __shared__ float sm[8];
  if ((t & 63) == 0) { sm[t >> 6] = s; sm[4 + (t >> 6)] = q; }
  __syncthreads();
  if (t == 0) {
    s = sm[0] + sm[1] + sm[2] + sm[3];
    q = sm[4] + sm[5] + sm[6] + sm[7];
    float mean = s * (1.0f / 1024.0f);
    float var  = q * (1.0f / 1024.0f) - mean * mean;
    stats[row] = make_float2(mean, rsqrtf(var + 1e-5f));
  }
}

// xln[i] = bf16((x[i]-mu)*rstd*g+b), 8 elems/thread (all within one row).
__global__ __launch_bounds__(256) void ln_apply(
    const float* __restrict__ x, const float2* __restrict__ stats,
    const float* __restrict__ g, const float* __restrict__ b,
    bf16* __restrict__ out)
{
  long i = ((long)blockIdx.x * 256 + threadIdx.x) * 8;
  int row = (int)(i >> 10), col = (int)(i & 1023);
  float2 st = stats[row];
  float4 a0 = *(const float4*)(x + i);
  float4 a1 = *(const float4*)(x + i + 4);
  float4 g0 = *(const float4*)(g + col);
  float4 g1 = *(const float4*)(g + col + 4);
  float4 b0 = *(const float4*)(b + col);
  float4 b1 = *(const float4*)(b + col + 4);
  float av[8] = {a0.x, a0.y, a0.z, a0.w, a1.x, a1.y, a1.z, a1.w};
  float gv[8] = {g0.x, g0.y, g0.z, g0.w, g1.x, g1.y, g1.z, g1.w};
  float bv[8] = {b0.x, b0.y, b0.z, b0.w, b1.x, b1.y, b1.z, b1.w};
  short8 o;
#pragma unroll
  for (int j = 0; j < 8; j++)
    o[j] = f2s((av[j] - st.x) * st.y * gv[j] + bv[j]);
  *(short8*)(out + i) = o;
}

// LN stats, bf16 input.
__global__ __launch_bounds__(256) void ln_stats_b16(
    const bf16* __restrict__ x, float2* __restrict__ stats)
{
  int row = blockIdx.x, t = threadIdx.x;
  const bf16* xr = x + (long)row * 1024;
  float v[4];
#pragma unroll
  for (int i = 0; i < 4; i++) v[i] = b2f(xr[t * 4 + i]);
  float s = v[0] + v[1] + v[2] + v[3];
  float q = v[0] * v[0] + v[1] * v[1] + v[2] * v[2] + v[3] * v[3];
  for (int o = 32; o > 0; o >>= 1) { s += __shfl_down(s, o); q += __shfl_down(q, o); }
  __shared__ float sm[8];
  if ((t & 63) == 0) { sm[t >> 6] = s; sm[4 + (t >> 6)] = q; }
  __syncthreads();
  if (t == 0) {
    s = sm[0] + sm[1] + sm[2] + sm[3];
    q = sm[4] + sm[5] + sm[6] + sm[7];
    float mean = s * (1.0f / 1024.0f);
    float var  = q * (1.0f / 1024.0f) - mean * mean;
    stats[row] = make_float2(mean, rsqrtf(var + 1e-5f));
  }
}

// softmax over 256 contiguous elems per row (q~, per-head seg). In place, bf16.
__global__ __launch_bounds__(256) void qsoftmax256(bf16* __restrict__ q)
{
  long idx = (long)blockIdx.x * 256 + threadIdx.x;
  int t = threadIdx.x;
  float v = expf(0.25f * b2f(q[idx]));
  float s = v;
  for (int o = 32; o > 0; o >>= 1) s += __shfl_down(s, o);
  __shared__ float sm[4];
  if ((t & 63) == 0) sm[t >> 6] = s;
  __syncthreads();
  float tot = sm[0] + sm[1] + sm[2] + sm[3];
  q[idx] = f2b(v / tot);
}

// k softmax on fused KV buffer [4b][512e][4096n]: rows e<256 of each batch
// are k~; row-softmax exp(0.25x)/rowsum in place.
__global__ __launch_bounds__(256) void ksoftmaxKV(bf16* __restrict__ kv)
{
  int b = blockIdx.x >> 8, e = blockIdx.x & 255;
  long base = ((long)b * 512 + e) * 4096;
  int t = threadIdx.x;
  float loc[16];
  float s = 0.0f;
#pragma unroll
  for (int i = 0; i < 16; i++) {
    loc[i] = expf(0.25f * b2f(kv[base + t + i * 256]));
    s += loc[i];
  }
  for (int o = 32; o > 0; o >>= 1) s += __shfl_down(s, o);
  __shared__ float sm[4];
  if ((t & 63) == 0) sm[t >> 6] = s;
  __syncthreads();
  float inv = 1.0f / (sm[0] + sm[1] + sm[2] + sm[3]);
#pragma unroll
  for (int i = 0; i < 16; i++)
    kv[base + t + i * 256] = f2b(loc[i] * inv);
}

// ctx reduce: dst[b*262144 + j] = sum_{kc<16} G[kc*262144 + b*65536 + j].
// dst base is CTXT + h*65536 (head-interleaved [b][h][256d][256e]).
__global__ __launch_bounds__(256) void reduce_ctx(
    const bf16* __restrict__ G, bf16* __restrict__ dst)
{
  long i = (long)blockIdx.x * 256 + threadIdx.x;  // [0, 262144)
  float s = 0.0f;
#pragma unroll
  for (int kc = 0; kc < 16; kc++) s += b2f(G[kc * 262144 + i]);
  dst[(i >> 16) * 262144 + (i & 65535)] = f2b(s);
}

// OB[n] = sum_k b2[k] * wdt[n][k] + bd[n]   (n = blockIdx.x; wdt row stride ld)
__global__ __launch_bounds__(256) void out_bias(
    const float* __restrict__ b2, const bf16* __restrict__ wdt, int ld,
    const float* __restrict__ bd, float* __restrict__ OB)
{
  int n = blockIdx.x, t = threadIdx.x;
  const bf16* wr = wdt + (long)n * ld;
  float s = 0.0f;
#pragma unroll
  for (int i = 0; i < 4; i++) {
    int k = t * 4 + i;
    s += b2[k] * b2f(wr[k]);
  }
  for (int o = 32; o > 0; o >>= 1) s += __shfl_down(s, o);
  __shared__ float sm[4];
  if ((t & 63) == 0) sm[t >> 6] = s;
  __syncthreads();
  if (t == 0) OB[n] = sm[0] + sm[1] + sm[2] + sm[3] + bd[n];
}

// out[r][c] = b[c] over 1024x1024 fp32 (seed for atomic split-K GEMMs)
__global__ __launch_bounds__(256) void bias_bcast(
    const float* __restrict__ b, float* __restrict__ out)
{
  long i = ((long)blockIdx.x * 256 + threadIdx.x) * 4;
  *(float4*)(out + i) = *(const float4*)(b + (int)(i & 1023));
}

extern "C" void kernel_launch(void* const* d_in, const int* in_sizes, int n_in,
                              void* d_out, int out_size, void* d_ws, size_t ws_size,
                              hipStream_t stream) {
  const float* x    = (const float*)d_in[0];
  const float* ln1g = (const float*)d_in[1];
  const float* ln1b = (const float*)d_in[2];
  const float* wq   = (const float*)d_in[3];
  const float* wk   = (const float*)d_in[4];
  const float* wv   = (const float*)d_in[5];
  const float* wo   = (const float*)d_in[6];
  const float* bo   = (const float*)d_in[7];
  const float* ln2g = (const float*)d_in[8];
  const float* ln2b = (const float*)d_in[9];
  const float* wff1 = (const float*)d_in[10];
  const float* bff1 = (const float*)d_in[11];
  const float* wff2 = (const float*)d_in[12];
  const float* bff2 = (const float*)d_in[13];
  const float* wd   = (const float*)d_in[14];
  const float* bd   = (const float*)d_in[15];

  // d_out (64MB fp32) as scratch: first half xln (bf16 LN1(x)), second x2.
  bf16* xln = (bf16*)d_out;                           // 16384x1024 bf16
  bf16* x2  = (bf16*)d_out + (size_t)16384 * 1024;    // 16384x1024 bf16
  float* outf = (float*)d_out;

  char* wsp = (char*)d_ws;
  size_t off = 0;
  auto alloc = [&](size_t bytes) -> void* {
    void* p = wsp + off; off += (bytes + 255) & ~(size_t)255; return p;
  };
  bf16*   S1  = (bf16*)alloc((size_t)8 * 1024 * 1024);    // KV lo | q~ lo | wff1T
  bf16*   S2  = (bf16*)alloc((size_t)10 * 1024 * 1024);   // KV hi | q~ hi | WB
  bf16*   G   = (bf16*)alloc((size_t)10 * 1024 * 1024);   // ctx partials | CWT | [g|x2_R]
  bf16*   CTX = (bf16*)alloc((size_t)4 * 256 * 256 * 2);  // OB overlay (FFN)
  bf16*   W1  = (bf16*)alloc((size_t)1024 * 256 * 2);     // (spare)
  float2* st1 = (float2*)alloc((size_t)16384 * 8);
  float2* st2 = (float2*)alloc((size_t)16384 * 8);
  bf16*   KV   = S1;                           // [4b][512e][4096n] = 16MB (S1+S2)
  bf16*   W1kv = G + (size_t)9 * 512 * 1024;   // G bytes [9MB,10MB): [512][1024]
  bf16*   CTXT = S2 + (size_t)4 * 1024 * 1024; // S2 bytes [8MB,10MB): [4b][4h][256][256]
  bf16*   woT  = G + (size_t)4 * 1024 * 1024;  // G bytes [8MB,10MB): [1024][1024]
  bf16*   CWT  = G;                            // G bytes [0,8MB): [4b][1024c][1024hd]
  bf16*   wqT  = CTXT;                         // reuse after CWT built
  bf16*   QB   = S1;                           // q~ pair buffer [8192][1024] (16MB)
  bf16*   WB   = S2;                           // FFN: [1024][5120] = [WCD^T|wd^T]
  float*  OB   = (float*)CTX;                  // 4KB, FFN phase
  // total ws = 30,670,848 B — identical to the proven baseline footprint.

  const long SA  = (long)4096 * 1024;  // per-batch xln row stride (elements)
  const long PKV = (long)512 * 4096;   // per-batch KV [e][n] stride
  dim3 tb(32, 8);
  const bf16* nb = nullptr;

  // ---- LN1 stats + xln = bf16(LN1(x)) ----
  ln_stats_f32<<<16384, 256, 0, stream>>>(x, st1);
  ln_apply<<<8192, 256, 0, stream>>>(x, st1, ln1g, ln1b, xln);

  // ---- attention phase 1: per head, KV + context[d][e] ----
  for (int h = 0; h < 4; h++) {
    // KV = (xln @ [wk_h|wv_h])^T -> [4b][512e][4096n]; k rows then v rows.
    transpose_f2b<<<dim3(8, 32), tb, 0, stream>>>(wk + h * 256, W1kv, 1024, 1024);
    transpose_f2b<<<dim3(8, 32), tb, 0, stream>>>(wv + h * 256, W1kv + 256 * 1024, 1024, 1024);
    gemm_bt<1, 0, 0, 0><<<dim3(4, 32, 4), 256, 0, stream>>>(xln, W1kv, KV,
        1024, 1024, 1024, 4096, 2, 0, SA, 0, 0, 0, PKV,
        nullptr, nb, 0, nullptr, nullptr, nullptr);
    ksoftmaxKV<<<1024, 256, 0, stream>>>(KV);

    // ctx partials: G[kc][b][d][e] = sum_{n in kc} k~[d][n] * v[e][n]
    // (16 seq-chunks of 256 -> 256 blocks)
    gemm_bt<0, 0, 0, 0><<<dim3(2, 2, 64), 256, 0, stream>>>(KV, KV + (long)256 * 4096, G,
        256, 4096, 4096, 256, 4, PKV, 256, PKV, 256, 65536, 262144,
        nullptr, nb, 0, nullptr, nullptr, nullptr);
    reduce_ctx<<<1024, 256, 0, stream>>>(G, CTXT + h * 65536);
  }

  // ---- attention phase 1.5: CWT[b][c][(h,d)] = sum_e wo_h[e][c]*ctx_h[d][e] ----
  transpose_f2b<<<dim3(32, 32), tb, 0, stream>>>(wo, woT, 1024, 1024);
  gemm_bt<0, 0, 0, 0><<<dim3(2, 8, 16), 256, 0, stream>>>(woT, CTXT, CWT,
      256, 1024, 256, 1024, 2, 0, 256, 262144, 65536, 1048576, 256,
      nullptr, nb, 0, nullptr, nullptr, nullptr);
  transpose_f2b<<<dim3(32, 32), tb, 0, stream>>>(wq, wqT, 1024, 1024);  // CTXT dead

  // ---- attention phase 2: per batch-pair, q~ (all heads) then x2 ----
  for (int p = 0; p < 2; p++) {
    // q = xln_pair @ wq (all heads) -> QB [8192][1024]
    gemm_bt<0, 0, 0, 0><<<dim3(8, 64, 1), 256, 0, stream>>>(
        xln + (size_t)p * 8192 * 1024, wqT, QB,
        1024, 1024, 1024, 1024, 0, 0, 0, 0, 0, 0, 0,
        nullptr, nb, 0, nullptr, nullptr, nullptr);
    qsoftmax256<<<32768, 256, 0, stream>>>(QB);
    // x2_pair = x_pair + bo + q~ @ CWT[b]  (z = batch-in-pair)
    gemm_bt<0, 0, 0, 0, 1><<<dim3(8, 32, 2), 256, 0, stream>>>(
        QB, CWT + (size_t)p * 2 * 1048576, x2 + (size_t)p * 8192 * 1024,
        1024, 1024, 1024, 1024, 1, 0, SA, 0, 1048576, 0, SA,
        bo, (const bf16*)(x + (size_t)p * 8192 * 1024), 0,
        nullptr, nullptr, nullptr);
  }

  // ---- FFN + trailing dense: out = [g|x2_R] @ [WCD^T|wd^T]^T + OB ----
  ln_stats_b16<<<16384, 256, 0, stream>>>(x2, st2);
  transpose_f2b<<<dim3(128, 32), tb, 0, stream>>>(wff1, S1, 4096, 1024);  // S1 = wff1T
  // WB cols [4096:5120) = wd^T  (row stride 5120)
  transpose_f2b<<<dim3(32, 32), tb, 0, stream>>>(wd, WB + 4096, 1024, 5120);
  // WB cols [0:4096) = WCD^T = (wff2@wd)^T; B operand = wd^T slice of WB.
  gemm_bt<1, 1, 0, 0><<<dim3(8, 32, 1), 256, 0, stream>>>(wff2, WB + 4096, WB,
      1024, 1024, 5120, 5120, 0, 0, 0, 0, 0, 0, 0,
      nullptr, nb, 0, nullptr, nullptr, nullptr);
  // OB[n] = b_ff2 @ wd + b_d
  out_bias<<<1024, 256, 0, stream>>>(bff2, WB + 4096, 5120, bd, OB);

  for (int R = 0; R < 16; R++) {
    const bf16* xr = x2 + (size_t)R * 1024 * 1024;  // x2 rows (bf16)
    float* outR = outf + (size_t)R * 1024 * 1024;
    if (R < 15) {
      // prep: G cols [4096:5120) = x2_R; out_R = OB. Seed-clobber of x2 rows
      // [2048R-16384,2048R-14336) is below prep's own read rows for R<15.
      ffn_prep<<<1024, 256, 0, stream>>>(xr, OB, G, outR);
    } else {
      // R=15: seed clobbers x2 rows prep reads -> copy first, then seed.
      copy_cols<<<1024, 128, 0, stream>>>(xr, G);
      bias_bcast<<<1024, 256, 0, stream>>>(OB, outR);
    }
    // G cols [0:4096) = gelu(LN2(x2_R) @ wff1T + b1); A = rescued x2 copy.
    gemm_bt<0, 0, 0, 0><<<dim3(32, 8, 1), 256, 0, stream>>>(G + 4096, S1, G,
        1024, 5120, 1024, 5120, 2, 0, 0, 0, 0, 0, 0,
        bff1, nb, 1, st2 + R * 1024, ln2g, ln2b);
    // out_R += [g|x2_R] @ WB^T  (split-K: z=4 slices of K=1280 -> 256 blocks)
    gemm_bt<0, 0, 1, 1><<<dim3(8, 8, 4), 256, 0, stream>>>(G, WB, outR,
        1280, 5120, 5120, 1024, 2, 0, 1280, 0, 1280, 0, 0,
        nullptr, nb, 0, nullptr, nullptr, nullptr);
  }
}